// Round 26
// baseline (7870.589 us; speedup 1.0000x reference)
//
#include <hip/hip_runtime.h>

// r26: MFMA split-precision (r19, verified) + dual-chain slot pipeline
// (r20, verified). r19 was 2-phase ping-pong: G1 waves idle during G2's
// phase (3070cy/eval, 6% MfmaUtil). Here block owns 32 rows = 2 chains x 16;
// each slot G1 serves chain C (GEMM1+tanh->aP[C]) while G2 serves the other
// (aP->GEMM2+RK4->xP), 1 barrier/slot, 8 slots/step for BOTH chains ->
// eval wall ~= max(G1,G2) not sum. MFMA reads AGPR operands natively: the
// VALU family's unavoidable accvgpr-move tax (r24 assembler-proven) is zero.
// 32 blocks x 512 thr. Single-buffered per-chain xP/aP (1-barrier
// separation, traced). G1 bars = 1+8n+1; G2 = 2+8n.

typedef _Float16 h8 __attribute__((ext_vector_type(8)));
typedef float f4 __attribute__((ext_vector_type(4)));

#define NB 1024
#define ND 64
#define NH 256
#define RPB 32
#define NBLK 32
#define NTHR 512
#define LO_SC 2048.0f
#define LO_ISC 4.8828125e-4f   // 2^-11

#define MFMA16(A, B, C) __builtin_amdgcn_mfma_f32_16x16x32_f16((A), (B), (C), 0, 0, 0)
#define PIN(X) asm volatile("" : "+v"(X))

#define BSYNC() do { \
    asm volatile("s_waitcnt lgkmcnt(0)" ::: "memory"); \
    __builtin_amdgcn_s_barrier(); \
    asm volatile("" ::: "memory"); \
} while (0)

__device__ __forceinline__ float fast_tanh(float x) {
    float e = __expf(2.0f * x);
    float r = __builtin_amdgcn_rcpf(e + 1.0f);
    return 1.0f - 2.0f * r;
}

__global__ __launch_bounds__(NTHR, 2)
void node_rk4_mfma(const float* __restrict__ y0,
                   const float* __restrict__ t,
                   const float* __restrict__ W1,
                   const float* __restrict__ b1,
                   const float* __restrict__ W2,
                   const float* __restrict__ b2,
                   float* __restrict__ out, int nsteps)
{
    // A-frag staging per chain: [C][kt][lane][j] = elem (m=lane&15,
    // k=kt*32+(lane>>4)*8+j). xP: K=64 (2 kt). aP: K=256 (8 kt).
    __shared__ __align__(16) _Float16 xPh[2][2][64][8], xPl[2][2][64][8]; // 8 KB
    __shared__ __align__(16) _Float16 aPh[2][8][64][8], aPl[2][8][64][8]; // 32 KB

    const int tid = threadIdx.x;
    const int w  = tid >> 6, l = tid & 63;
    const int ln = l & 15,  lg = l >> 4;

    if (w < 4) {
        // ========== G1: aP[C] = split(tanh(xP[C] @ W1 + b1)) ==========
        h8 WH0,WH1,WH2,WH3,WH4,WH5,WH6,WH7;
        h8 WL0,WL1,WL2,WL3,WL4,WL5,WL6,WL7;
#define LG1(NT,KT,H,L) { \
        int n_ = (w<<6) + ((NT)<<4) + ln; \
        int kb_ = (KT)*32 + lg*8; \
        _Pragma("unroll") for (int j=0;j<8;++j) { \
            float f_ = W1[(kb_+j)*NH + n_]; \
            _Float16 fh_ = (_Float16)f_; \
            H[j] = fh_; L[j] = (_Float16)((f_-(float)fh_)*LO_SC); } }
        LG1(0,0,WH0,WL0) LG1(0,1,WH1,WL1)
        LG1(1,0,WH2,WL2) LG1(1,1,WH3,WL3)
        LG1(2,0,WH4,WL4) LG1(2,1,WH5,WL5)
        LG1(3,0,WH6,WL6) LG1(3,1,WH7,WL7)
        PIN(WH0);PIN(WH1);PIN(WH2);PIN(WH3);PIN(WH4);PIN(WH5);PIN(WH6);PIN(WH7);
        PIN(WL0);PIN(WL1);PIN(WL2);PIN(WL3);PIN(WL4);PIN(WL5);PIN(WL6);PIN(WL7);
        const float bv0 = b1[(w<<6) +  0 + ln];
        const float bv1 = b1[(w<<6) + 16 + ln];
        const float bv2 = b1[(w<<6) + 32 + ln];
        const float bv3 = b1[(w<<6) + 48 + ln];

        // scatter pointers (chain 0; chain 1 = +4096 halves)
        _Float16 *aph0,*aph1,*aph2,*aph3, *apl0,*apl1,*apl2,*apl3;
#define SPTR(NT, PH, PL) { \
        int n_ = (w<<6) + ((NT)<<4) + ln; \
        int kt_ = n_>>5, g_ = (n_>>3)&3, j_ = n_&7; \
        PH = &aPh[0][kt_][(g_<<4)+lg*4][j_]; \
        PL = &aPl[0][kt_][(g_<<4)+lg*4][j_]; }
        SPTR(0,aph0,apl0) SPTR(1,aph1,apl1) SPTR(2,aph2,apl2) SPTR(3,aph3,apl3)
        const h8* xp0h = (const h8*)&xPh[0][0][l][0];   // chain 1 = +128 h8
        const h8* xp1h = (const h8*)&xPh[0][1][l][0];
        const h8* xp0l = (const h8*)&xPl[0][0][l][0];
        const h8* xp1l = (const h8*)&xPl[0][1][l][0];

#define G1NT(C, PH, PL, HH0, HH1, LL0, LL1, BV) { \
            f4 aH = {BV,BV,BV,BV}; \
            aH = MFMA16(xh0, HH0, aH);  aH = MFMA16(xh1, HH1, aH); \
            f4 aL1 = MFMA16(xl0, HH0, zz); aL1 = MFMA16(xl1, HH1, aL1); \
            f4 aL2 = MFMA16(xh0, LL0, zz); aL2 = MFMA16(xh1, LL1, aL2); \
            f4 hv = aH + LO_ISC*(aL1 + aL2); \
            _Pragma("unroll") for (int r=0;r<4;++r) { \
                float a_ = fast_tanh(hv[r]); \
                _Float16 ah_ = (_Float16)a_; \
                PH[(C)*4096 + r*8] = ah_; \
                PL[(C)*4096 + r*8] = (_Float16)((a_-(float)ah_)*LO_SC); } }
#define G1SLOT(C) { \
            h8 xh0 = xp0h[(C)*128], xh1 = xp1h[(C)*128]; \
            h8 xl0 = xp0l[(C)*128], xl1 = xp1l[(C)*128]; \
            f4 zz = {0.f,0.f,0.f,0.f}; \
            G1NT(C, aph0, apl0, WH0, WH1, WL0, WL1, bv0) \
            G1NT(C, aph1, apl1, WH2, WH3, WL2, WL3, bv1) \
            G1NT(C, aph2, apl2, WH4, WH5, WL4, WL5, bv2) \
            G1NT(C, aph3, apl3, WH6, WH7, WL6, WL7, bv3) }

        BSYNC();   // bar0: initial xP ready
        for (int s = 0; s < nsteps; ++s) {
            G1SLOT(0) BSYNC(); G1SLOT(1) BSYNC();
            G1SLOT(0) BSYNC(); G1SLOT(1) BSYNC();
            G1SLOT(0) BSYNC(); G1SLOT(1) BSYNC();
            G1SLOT(0) BSYNC(); G1SLOT(1) BSYNC();
        }
        BSYNC();   // final slot: G2 finishes chain 1 ST4 while G1 idles
    } else {
        // ========== G2: k = aP[C] @ W2 + b2; RK4 state in registers ==========
        const int g2 = w - 4;
        const int d  = (g2<<4) + ln;          // owned output dim
        h8 VH0,VH1,VH2,VH3,VH4,VH5,VH6,VH7;
        h8 VL0,VL1,VL2,VL3,VL4,VL5,VL6,VL7;
#define LG2(KT,H,L) { \
        int kb_ = (KT)*32 + lg*8; \
        _Pragma("unroll") for (int j=0;j<8;++j) { \
            float f_ = W2[(kb_+j)*ND + d]; \
            _Float16 fh_ = (_Float16)f_; \
            H[j] = fh_; L[j] = (_Float16)((f_-(float)fh_)*LO_SC); } }
        LG2(0,VH0,VL0) LG2(1,VH1,VL1) LG2(2,VH2,VL2) LG2(3,VH3,VL3)
        LG2(4,VH4,VL4) LG2(5,VH5,VL5) LG2(6,VH6,VL6) LG2(7,VH7,VL7)
        PIN(VH0);PIN(VH1);PIN(VH2);PIN(VH3);PIN(VH4);PIN(VH5);PIN(VH6);PIN(VH7);
        PIN(VL0);PIN(VL1);PIN(VL2);PIN(VL3);PIN(VL4);PIN(VL5);PIN(VL6);PIN(VL7);
        const float b2v = b2[d];

        // aP read pointers (chain 0; chain 1 = +512 h8)
        const h8 *pa0 = (const h8*)&aPh[0][0][l][0], *pa1 = (const h8*)&aPh[0][1][l][0];
        const h8 *pa2 = (const h8*)&aPh[0][2][l][0], *pa3 = (const h8*)&aPh[0][3][l][0];
        const h8 *pa4 = (const h8*)&aPh[0][4][l][0], *pa5 = (const h8*)&aPh[0][5][l][0];
        const h8 *pa6 = (const h8*)&aPh[0][6][l][0], *pa7 = (const h8*)&aPh[0][7][l][0];
        const h8 *pc0 = (const h8*)&aPl[0][0][l][0], *pc1 = (const h8*)&aPl[0][1][l][0];
        const h8 *pc2 = (const h8*)&aPl[0][2][l][0], *pc3 = (const h8*)&aPl[0][3][l][0];
        const h8 *pc4 = (const h8*)&aPl[0][4][l][0], *pc5 = (const h8*)&aPl[0][5][l][0];
        const h8 *pc6 = (const h8*)&aPl[0][6][l][0], *pc7 = (const h8*)&aPl[0][7][l][0];

        // RK4 state, D-frag layout: lane holds y[m=4*lg+r][d] per chain.
        const size_t rb = (size_t)blockIdx.x * RPB * ND;
        f4 ys0, ka0, ys1, ka1;
        #pragma unroll
        for (int r=0;r<4;++r) {
            float v0 = y0[rb + (size_t)(4*lg+r)*ND + d];
            ys0[r] = v0; out[rb + (size_t)(4*lg+r)*ND + d] = v0;
            float v1 = y0[rb + (size_t)(16+4*lg+r)*ND + d];
            ys1[r] = v1; out[rb + (size_t)(16+4*lg+r)*ND + d] = v1;
        }
        const int xkt = g2 >> 1;
        const int xg  = 2*(g2&1) + (ln>>3);
        const int xj  = ln & 7;
        _Float16* xph = &xPh[0][xkt][(xg<<4)+lg*4][xj];   // chain 1 = +1024 halves
        _Float16* xpl = &xPl[0][xkt][(xg<<4)+lg*4][xj];
#define PACKX(C, XV, R) { \
        float xv_ = (XV); \
        _Float16 xh_ = (_Float16)xv_; \
        xph[(C)*1024 + (R)*8] = xh_; \
        xpl[(C)*1024 + (R)*8] = (_Float16)((xv_-(float)xh_)*LO_SC); }
        #pragma unroll
        for (int r=0;r<4;++r) { PACKX(0, ys0[r], r) PACKX(1, ys1[r], r) }
        BSYNC();   // bar0
        BSYNC();   // slot0: G1 fills aP[0]; G2 idle

        for (int s = 0; s < nsteps; ++s) {
            float dt = t[s+1] - t[s];
            size_t ob = (size_t)(s+1)*(NB*ND) + rb;
#define G2EVAL(C, ST) { \
            h8 a0=pa0[(C)*512],a1=pa1[(C)*512],a2=pa2[(C)*512],a3=pa3[(C)*512]; \
            h8 a4=pa4[(C)*512],a5=pa5[(C)*512],a6=pa6[(C)*512],a7=pa7[(C)*512]; \
            h8 c0=pc0[(C)*512],c1=pc1[(C)*512],c2=pc2[(C)*512],c3=pc3[(C)*512]; \
            h8 c4=pc4[(C)*512],c5=pc5[(C)*512],c6=pc6[(C)*512],c7=pc7[(C)*512]; \
            f4 zz = {0.f,0.f,0.f,0.f}; \
            f4 HA=MFMA16(a0,VH0,zz), HB=MFMA16(a1,VH1,zz); \
            f4 HC=MFMA16(a2,VH2,zz), HD=MFMA16(a3,VH3,zz); \
            HA=MFMA16(a4,VH4,HA); HB=MFMA16(a5,VH5,HB); \
            HC=MFMA16(a6,VH6,HC); HD=MFMA16(a7,VH7,HD); \
            f4 LA=MFMA16(c0,VH0,zz), LB=MFMA16(c1,VH1,zz); \
            f4 LC=MFMA16(c2,VH2,zz), LD=MFMA16(c3,VH3,zz); \
            LA=MFMA16(c4,VH4,LA); LB=MFMA16(c5,VH5,LB); \
            LC=MFMA16(c6,VH6,LC); LD=MFMA16(c7,VH7,LD); \
            f4 MA=MFMA16(a0,VL0,zz), MB=MFMA16(a1,VL1,zz); \
            f4 MC=MFMA16(a2,VL2,zz), MD=MFMA16(a3,VL3,zz); \
            MA=MFMA16(a4,VL4,MA); MB=MFMA16(a5,VL5,MB); \
            MC=MFMA16(a6,VL6,MC); MD=MFMA16(a7,VL7,MD); \
            f4 kv = ((HA+HB)+(HC+HD)) \
                  + LO_ISC*(((LA+LB)+(LC+LD)) + ((MA+MB)+(MC+MD))); \
            _Pragma("unroll") for (int r=0;r<4;++r) kv[r] += b2v; \
            f4 xn; \
            if ((ST)==1)      { ka##C = kv;        xn = ys##C + (0.5f*dt)*kv; } \
            else if ((ST)==2) { ka##C += 2.0f*kv;  xn = ys##C + (0.5f*dt)*kv; } \
            else if ((ST)==3) { ka##C += 2.0f*kv;  xn = ys##C + dt*kv; } \
            else { ys##C = ys##C + (dt*(1.0f/6.0f))*(ka##C + kv); xn = ys##C; \
                   _Pragma("unroll") for (int r=0;r<4;++r) \
                       out[ob + (size_t)((C)*16 + 4*lg+r)*ND + d] = ys##C[r]; } \
            _Pragma("unroll") for (int r=0;r<4;++r) PACKX(C, xn[r], r) }
            G2EVAL(0,1) BSYNC(); G2EVAL(1,1) BSYNC();
            G2EVAL(0,2) BSYNC(); G2EVAL(1,2) BSYNC();
            G2EVAL(0,3) BSYNC(); G2EVAL(1,3) BSYNC();
            G2EVAL(0,4) BSYNC(); G2EVAL(1,4) BSYNC();
        }
    }
}

extern "C" void kernel_launch(void* const* d_in, const int* in_sizes, int n_in,
                              void* d_out, int out_size, void* d_ws, size_t ws_size,
                              hipStream_t stream) {
    const float* y0 = (const float*)d_in[0];
    const float* t  = (const float*)d_in[1];
    const float* W1 = (const float*)d_in[2];
    const float* b1 = (const float*)d_in[3];
    const float* W2 = (const float*)d_in[4];
    const float* b2 = (const float*)d_in[5];
    float* out = (float*)d_out;
    int nsteps = in_sizes[1] - 1;
    hipLaunchKernelGGL(node_rk4_mfma, dim3(NBLK), dim3(NTHR), 0, stream,
                       y0, t, W1, b1, W2, b2, out, nsteps);
}